// Round 6
// baseline (121.069 us; speedup 1.0000x reference)
//
#include <hip/hip_runtime.h>
#include <math.h>

#define BINS 10

// Problem constants: BATCH=8388608, NUM_CLASSES=2
constexpr int   NPAIRS = 4194304;       // float4 quads (2 rows x 2 classes each)
constexpr float NTOT_F = 16777216.0f;   // BATCH * NUM_CLASSES

constexpr int G1     = 2048;
constexpr int BLK    = 256;
constexpr int STRIDE = G1 * BLK;        // 524288
constexpr int ITERS  = NPAIRS / STRIDE; // 8 exact -> fully unrolled, no tail
// elements/thread = 32 -> 6-bit packed count fields can't overflow (<=32 < 64)

// Workspace: blk_pair[b*G1 + block] = {f32 bce-sum(log2), u32 count} -- 160 KB
constexpr size_t WS_PAIR = 0;

struct alignas(8) Pair { float s; unsigned c; };

// Pure-register element processing (R4/R5 lessons: LDS atomics ~10x trap,
// LDS RMW latency-chains; 10 VGPR accumulators + cndmask is the fast path).
__device__ __forceinline__ void proc(float x, bool y1,
                                     float* __restrict__ acc,
                                     unsigned long long& cnt64) {
    // z = (y==1) ? -x : x ; t = e^z ; u = 1+t
    // g = |sigmoid(x)-y| = t/u ; bce = max(x,0)-x*y+log1p(e^-|x|) = ln(u) = ln2*log2(u)
    float z = y1 ? -x : x;
    float t = __builtin_amdgcn_exp2f(z * 1.4426950408889634f);
    float u = 1.0f + t;
    float g = t * __builtin_amdgcn_rcpf(u);
    int   b = (int)(g * 9.9999f);        // g in [0,1] -> trunc == floor
    b = b < 9 ? b : 9;                   // clamp (rcp rounding safety)
    float l = __builtin_amdgcn_logf(u);  // log2(u); ln2 applied once at the end
    // 6*b via shifts (avoid quarter-rate v_mul_lo_u32)
    unsigned sh = ((unsigned)b << 2) + ((unsigned)b << 1);
    cnt64 += 1ull << sh;                 // all 10 counts packed in one u64
#pragma unroll
    for (int i = 0; i < BINS; ++i)       // v_cmp + v_cndmask + v_add each
        acc[i] += (b == i) ? l : 0.0f;
}

__global__ __launch_bounds__(BLK) void ghm_main(const float4* __restrict__ x4,
                                                const int2*   __restrict__ t2,
                                                Pair*         __restrict__ blk_pair) {
    const int tid  = threadIdx.x;
    const int lane = tid & 63;
    const int wave = tid >> 6;

    // ---- phase 1: issue ALL global loads before any dependent compute ----
    // 16 outstanding dwordx4/dwordx2 per thread -> memory latency overlapped
    // with nothing blocking issue; compute phase then runs against warm regs.
    float4 xv[ITERS];
    int2   tv[ITERS];
    const int base = blockIdx.x * BLK + tid;
#pragma unroll
    for (int k = 0; k < ITERS; ++k) {
        xv[k] = x4[base + k * STRIDE];
        tv[k] = t2[base + k * STRIDE];
    }

    // ---- phase 2: pure-VALU accumulation ----
    float acc[BINS];
#pragma unroll
    for (int b = 0; b < BINS; ++b) acc[b] = 0.0f;
    unsigned long long cnt64 = 0ull;

#pragma unroll
    for (int k = 0; k < ITERS; ++k) {
        // element (row, c): y = (target[row] == c)
        proc(xv[k].x, tv[k].x == 0, acc, cnt64);
        proc(xv[k].y, tv[k].x == 1, acc, cnt64);
        proc(xv[k].z, tv[k].y == 0, acc, cnt64);
        proc(xv[k].w, tv[k].y == 1, acc, cnt64);
    }

    // unpack counts, then 64-lane shuffle-tree reduce per bin (once per kernel)
    unsigned cnt[BINS];
#pragma unroll
    for (int b = 0; b < BINS; ++b) cnt[b] = (unsigned)((cnt64 >> (6 * b)) & 63ull);
#pragma unroll
    for (int b = 0; b < BINS; ++b) {
        for (int off = 32; off > 0; off >>= 1) {
            acc[b] += __shfl_down(acc[b], off, 64);
            cnt[b] += __shfl_down(cnt[b], off, 64);
        }
    }

    // tiny cross-wave reduce: 4 waves x 10 pairs in LDS (320 B)
    __shared__ Pair red[4][BINS];
    if (lane == 0) {
#pragma unroll
        for (int b = 0; b < BINS; ++b) red[wave][b] = Pair{acc[b], cnt[b]};
    }
    __syncthreads();
    if (tid < BINS) {
        float    s = red[0][tid].s + red[1][tid].s + red[2][tid].s + red[3][tid].s;
        unsigned c = red[0][tid].c + red[1][tid].c + red[2][tid].c + red[3][tid].c;
        blk_pair[tid * G1 + blockIdx.x] = Pair{s, c};   // bin-major for final kernel
    }
}

// Final: 10 waves (one per bin); 32 fully-unrolled independent dwordx2 loads per
// lane -> one memory round-trip; f64 shuffle reduce; thread 0 forms beta (ref
// fp32 arithmetic) and the weighted total. Deterministic.
__global__ __launch_bounds__(640) void ghm_final(const Pair* __restrict__ blk_pair,
                                                 float*      __restrict__ out) {
    const int wave = threadIdx.x >> 6;   // 0..9 = bin
    const int lane = threadIdx.x & 63;
    double s = 0.0, c = 0.0;
#pragma unroll
    for (int k = 0; k < G1 / 64; ++k) {
        Pair p = blk_pair[wave * G1 + k * 64 + lane];
        s += (double)p.s;
        c += (double)p.c;
    }
    for (int off = 32; off > 0; off >>= 1) {
        s += __shfl_down(s, off, 64);
        c += __shfl_down(c, off, 64);
    }
    __shared__ double Sb[BINS], Cb[BINS];
    if (lane == 0) { Sb[wave] = s; Cb[wave] = c; }
    __syncthreads();
    if (threadIdx.x == 0) {
        float nonempty = 0.0f;
#pragma unroll
        for (int b = 0; b < BINS; ++b) nonempty += (Cb[b] > 0.0) ? 1.0f : 0.0f;
        double tot = 0.0;
#pragma unroll
        for (int b = 0; b < BINS; ++b) {
            float gd   = fmaxf((float)Cb[b] * nonempty, 0.0001f);  // ref fp32 math
            float beta = NTOT_F / gd;
            tot += (double)beta * Sb[b];
        }
        // bce sums kept in log2; apply ln2 once, then mean
        out[0] = (float)(tot * 0.693147180559945309 / (double)NTOT_F);
    }
}

extern "C" void kernel_launch(void* const* d_in, const int* in_sizes, int n_in,
                              void* d_out, int out_size, void* d_ws, size_t ws_size,
                              hipStream_t stream) {
    const float4* x4 = (const float4*)d_in[0];   // [B,2] fp32 -> 2 rows per float4
    const int2*   t2 = (const int2*)d_in[1];     // int32 targets -> 2 rows per int2

    Pair*  blk_pair = (Pair*)((char*)d_ws + WS_PAIR);
    float* out      = (float*)d_out;

    ghm_main <<<G1, BLK, 0, stream>>>(x4, t2, blk_pair);
    ghm_final<<<1, 640, 0, stream>>>(blk_pair, out);
}